// Round 1
// baseline (1772.537 us; speedup 1.0000x reference)
//
#include <hip/hip_runtime.h>
#include <math.h>

#define B_SZ   256
#define T_SEQ  720
#define C_INN  862
#define RANK   32
#define FCUT   48
#define GOUT   96
// N_full = 1440, LENGTH_RATIO = 2

// ws layout (floats):
// [0, 5898240)          Y / z buffer (B*T*RANK)
// [5898240, 5967360)    ftab: 48*720 float2 (cos,sin of 2*pi*(f*t mod 720)/720)
// [5967360, 6105600)    itab: 720*96 float2 (cos,sin of 2*pi*(g*t mod 1440)/1440), t = 720+tl
#define Y_ELEMS   (5898240)
#define FTAB_OFF  (5898240)
#define ITAB_OFF  (5967360)

__global__ __launch_bounds__(256) void k_tabgen(float2* __restrict__ ftab,
                                                float2* __restrict__ itab) {
    int i = blockIdx.x * 256 + threadIdx.x;
    const float TWO_PI = 6.28318530717958647692f;
    if (i < FCUT * T_SEQ) {
        int f = i / T_SEQ;
        int t = i - f * T_SEQ;
        int m = (f * t) % T_SEQ;
        float th = TWO_PI * (float)m / (float)T_SEQ;
        float s, c;
        sincosf(th, &s, &c);
        ftab[i] = make_float2(c, s);
    } else {
        int j = i - FCUT * T_SEQ;   // < 720*96
        int tl = j / GOUT;
        int g  = j - tl * GOUT;
        int m = (g * (T_SEQ + tl)) % (2 * T_SEQ);
        float th = TWO_PI * (float)m / (float)(2 * T_SEQ);
        float s, c;
        sincosf(th, &s, &c);
        itab[j] = make_float2(c, s);
    }
}

// Y[row][c] = sum_k x[row][k] * P[k][c]; 32 rows per block (8 groups x 4 rows)
__global__ __launch_bounds__(256) void k_encode(const float* __restrict__ x,
                                                const float* __restrict__ P,
                                                float* __restrict__ Y) {
    int c  = threadIdx.x & 31;
    int rg = threadIdx.x >> 5;                 // 0..7
    long rowBase = (long)blockIdx.x * 32 + (long)rg * 4;
    const float* x0 = x + rowBase * C_INN;
    float a0 = 0.f, a1 = 0.f, a2 = 0.f, a3 = 0.f;
#pragma unroll 4
    for (int k = 0; k < C_INN; k += 2) {
        float2 v0 = *(const float2*)(x0 + k);
        float2 v1 = *(const float2*)(x0 + C_INN + k);
        float2 v2 = *(const float2*)(x0 + 2 * C_INN + k);
        float2 v3 = *(const float2*)(x0 + 3 * C_INN + k);
        float p0 = P[k * RANK + c];
        float p1 = P[(k + 1) * RANK + c];
        a0 += v0.x * p0 + v0.y * p1;
        a1 += v1.x * p0 + v1.y * p1;
        a2 += v2.x * p0 + v2.y * p1;
        a3 += v3.x * p0 + v3.y * p1;
    }
    float* y0 = Y + rowBase * RANK + c;
    y0[0]        = a0;
    y0[RANK]     = a1;
    y0[2 * RANK] = a2;
    y0[3 * RANK] = a3;
}

// One block per batch b. Stats -> normalize -> DFT(48) -> complex mix -> iDFT(720) -> denorm.
// Writes z in-place over Y (block only touches its own slice, fully loaded to LDS first).
__global__ __launch_bounds__(512) void k_freq(const float* __restrict__ Yg,
                                              float* __restrict__ Zg,
                                              const float2* __restrict__ ftab,
                                              const float2* __restrict__ itab,
                                              const float* __restrict__ Wr,
                                              const float* __restrict__ Wi,
                                              const float* __restrict__ brr,
                                              const float* __restrict__ bii) {
    __shared__ float Yb[T_SEQ * RANK];        // 92160 B
    __shared__ float Fre[FCUT * RANK];        // 6144
    __shared__ float Fim[FCUT * RANK];        // 6144
    __shared__ float Ore[GOUT * RANK];        // 12288
    __shared__ float Oim[GOUT * RANK];        // 12288
    __shared__ float red1[16 * 32];
    __shared__ float red2[16 * 32];
    __shared__ float meanS[RANK], stdS[RANK], istdS[RANK];

    int b   = blockIdx.x;
    int tid = threadIdx.x;
    const float* src = Yg + (size_t)b * T_SEQ * RANK;

    // load batch tile to LDS (coalesced float4)
    for (int i4 = tid; i4 < T_SEQ * RANK / 4; i4 += 512)
        ((float4*)Yb)[i4] = ((const float4*)src)[i4];
    __syncthreads();

    // stats
    {
        int r = tid & 31, grp = tid >> 5;     // 16 groups over t
        float s = 0.f, s2 = 0.f;
        for (int t = grp; t < T_SEQ; t += 16) {
            float v = Yb[t * RANK + r];
            s += v; s2 += v * v;
        }
        red1[grp * 32 + r] = s;
        red2[grp * 32 + r] = s2;
    }
    __syncthreads();
    if (tid < 32) {
        float s = 0.f, s2 = 0.f;
        for (int j = 0; j < 16; ++j) { s += red1[j * 32 + tid]; s2 += red2[j * 32 + tid]; }
        float mean = s / (float)T_SEQ;
        float var  = (s2 - (float)T_SEQ * mean * mean) / (float)(T_SEQ - 1);
        float sd   = sqrtf(var + 1e-5f);
        meanS[tid] = mean;
        stdS[tid]  = sd;
        istdS[tid] = 1.0f / sd;
    }
    __syncthreads();
    // normalize in place
    for (int e = tid; e < T_SEQ * RANK; e += 512) {
        int r = e & 31;
        Yb[e] = (Yb[e] - meanS[r]) * istdS[r];
    }
    __syncthreads();

    // forward DFT: F[f][r] = sum_t x[t][r] * e^{-2pi i f t/720}, f = 0..47
    {
        int r2 = tid & 15, fg = tid >> 4;     // 32 f-groups, 2 r per thread
        for (int f = fg; f < FCUT; f += 32) {
            float re0 = 0.f, im0 = 0.f, re1 = 0.f, im1 = 0.f;
            const float2* ft = ftab + f * T_SEQ;
#pragma unroll 4
            for (int t = 0; t < T_SEQ; ++t) {
                float2 y  = *(const float2*)(Yb + t * RANK + 2 * r2);
                float2 cs = ft[t];
                re0 += y.x * cs.x;  im0 -= y.x * cs.y;
                re1 += y.y * cs.x;  im1 -= y.y * cs.y;
            }
            Fre[f * RANK + 2 * r2]     = re0;
            Fre[f * RANK + 2 * r2 + 1] = re1;
            Fim[f * RANK + 2 * r2]     = im0;
            Fim[f * RANK + 2 * r2 + 1] = im1;
        }
    }
    __syncthreads();

    // complex mix: O[g][r] = sum_f F[f][r]*W[r][g][f] + b[r][g]
    {
        int r = tid & 31, gg = tid >> 5;      // 16 g-groups
        for (int g = gg; g < GOUT; g += 16) {
            float are = brr[r * GOUT + g];
            float aim = bii[r * GOUT + g];
            const float* wr = Wr + ((size_t)r * GOUT + g) * FCUT;
            const float* wi = Wi + ((size_t)r * GOUT + g) * FCUT;
#pragma unroll 4
            for (int f = 0; f < FCUT; ++f) {
                float fr = Fre[f * RANK + r], fi = Fim[f * RANK + r];
                float wrv = wr[f], wiv = wi[f];
                are += fr * wrv - fi * wiv;
                aim += fr * wiv + fi * wrv;
            }
            Ore[g * RANK + r] = are;
            Oim[g * RANK + r] = aim;
        }
    }
    __syncthreads();

    // inverse DFT (t = 720..1439), scale by LENGTH_RATIO/1440 = 1/720, denormalize, store
    {
        int r2 = tid & 15, tg = tid >> 4;     // 32 t-groups, 2 r per thread
        float m0  = meanS[2 * r2],  m1  = meanS[2 * r2 + 1];
        float sd0 = stdS[2 * r2],   sd1 = stdS[2 * r2 + 1];
        float dc0 = Ore[2 * r2],    dc1 = Ore[2 * r2 + 1];
        for (int tl = tg; tl < T_SEQ; tl += 32) {
            float s0 = 0.f, s1 = 0.f;
            const float2* it = itab + tl * GOUT;
#pragma unroll 4
            for (int g = 1; g < GOUT; ++g) {
                float2 cs  = it[g];
                float2 ore = *(const float2*)(Ore + g * RANK + 2 * r2);
                float2 oim = *(const float2*)(Oim + g * RANK + 2 * r2);
                s0 += ore.x * cs.x - oim.x * cs.y;
                s1 += ore.y * cs.x - oim.y * cs.y;
            }
            float v0 = (dc0 + 2.0f * s0) * (1.0f / 720.0f);
            float v1 = (dc1 + 2.0f * s1) * (1.0f / 720.0f);
            v0 = v0 * sd0 + m0;
            v1 = v1 * sd1 + m1;
            *(float2*)(Zg + (size_t)b * T_SEQ * RANK + tl * RANK + 2 * r2) = make_float2(v0, v1);
        }
    }
}

// out[row][c] = sum_k z[row][k] * D[k][c]; D columns live in registers
__global__ __launch_bounds__(256) void k_decode(const float* __restrict__ Z,
                                                const float* __restrict__ D,
                                                float* __restrict__ out) {
    int tid = threadIdx.x;
    int c0 = tid, c1 = tid + 256, c2 = tid + 512, c3 = tid + 768;
    bool v3 = (c3 < C_INN);
    float d0[RANK], d1[RANK], d2[RANK], d3[RANK];
#pragma unroll
    for (int k = 0; k < RANK; ++k) {
        d0[k] = D[k * C_INN + c0];
        d1[k] = D[k * C_INN + c1];
        d2[k] = D[k * C_INN + c2];
        d3[k] = v3 ? D[k * C_INN + c3] : 0.f;
    }
    long rowBase = (long)blockIdx.x * 128;
    for (int i = 0; i < 128; ++i) {
        long row = rowBase + i;
        const float* z = Z + row * RANK;
        float a0 = 0.f, a1 = 0.f, a2 = 0.f, a3 = 0.f;
#pragma unroll
        for (int k = 0; k < RANK; ++k) {
            float zv = z[k];
            a0 += zv * d0[k];
            a1 += zv * d1[k];
            a2 += zv * d2[k];
            a3 += zv * d3[k];
        }
        float* o = out + row * C_INN;
        o[c0] = a0;
        o[c1] = a1;
        o[c2] = a2;
        if (v3) o[c3] = a3;
    }
}

extern "C" void kernel_launch(void* const* d_in, const int* in_sizes, int n_in,
                              void* d_out, int out_size, void* d_ws, size_t ws_size,
                              hipStream_t stream) {
    const float* x   = (const float*)d_in[0];
    const float* P   = (const float*)d_in[1];
    const float* D   = (const float*)d_in[2];
    const float* Wr  = (const float*)d_in[3];
    const float* Wi  = (const float*)d_in[4];
    const float* brr = (const float*)d_in[5];
    const float* bii = (const float*)d_in[6];
    float* out = (float*)d_out;
    float* ws  = (float*)d_ws;

    float*  Y    = ws;
    float2* ftab = (float2*)(ws + FTAB_OFF);
    float2* itab = (float2*)(ws + ITAB_OFF);

    k_tabgen<<<405, 256, 0, stream>>>(ftab, itab);                 // 405*256 == 48*720 + 720*96
    k_encode<<<(B_SZ * T_SEQ) / 32, 256, 0, stream>>>(x, P, Y);    // 5760 blocks
    k_freq<<<B_SZ, 512, 0, stream>>>(Y, Y, ftab, itab, Wr, Wi, brr, bii);
    k_decode<<<(B_SZ * T_SEQ) / 128, 256, 0, stream>>>(Y, D, out); // 1440 blocks
}

// Round 2
// 764.872 us; speedup vs baseline: 2.3174x; 2.3174x over previous
//
#include <hip/hip_runtime.h>
#include <math.h>

#define B_SZ   256
#define T_SEQ  720
#define C_INN  862
#define RANK   32
#define FCUT   48
#define GOUT   96
// N_full = 1440, LENGTH_RATIO = 2

// ws layout (floats):
// [0, 5898240)            Y / z buffer (B*T*RANK)
// [5898240, 5967360)      ftab: 48*720 float2
// [5967360, 6105600)      itab: 720*96 float2
// [6105600, 6119424)      Pswz: 27648 bf16 (shorts) = 13824 floats
#define Y_ELEMS   (5898240)
#define FTAB_OFF  (5898240)
#define ITAB_OFF  (5967360)
#define PSWZ_OFF  (6105600)
#define KTILES    27            // ceil(862/32) -> K padded to 864

typedef __attribute__((ext_vector_type(8))) short bf16x8;
typedef __attribute__((ext_vector_type(4))) float f32x4;

__device__ inline short f2bf(float f) {
    union { float f; unsigned u; } v; v.f = f;
    unsigned r = (v.u + 0x7fffu + ((v.u >> 16) & 1u)) >> 16;   // RNE
    return (short)r;
}

__global__ __launch_bounds__(256) void k_tabgen(float2* __restrict__ ftab,
                                                float2* __restrict__ itab) {
    int i = blockIdx.x * 256 + threadIdx.x;
    const float TWO_PI = 6.28318530717958647692f;
    if (i < FCUT * T_SEQ) {
        int f = i / T_SEQ;
        int t = i - f * T_SEQ;
        int m = (f * t) % T_SEQ;
        float th = TWO_PI * (float)m / (float)T_SEQ;
        float s, c;
        sincosf(th, &s, &c);
        ftab[i] = make_float2(c, s);
    } else {
        int j = i - FCUT * T_SEQ;   // < 720*96
        int tl = j / GOUT;
        int g  = j - tl * GOUT;
        int m = (g * (T_SEQ + tl)) % (2 * T_SEQ);
        float th = TWO_PI * (float)m / (float)(2 * T_SEQ);
        float s, c;
        sincosf(th, &s, &c);
        itab[j] = make_float2(c, s);
    }
}

// Pre-swizzle P (862x32 f32) into bf16 MFMA B-fragment order:
// flat idx = ((kt*2+ct)*64 + lane)*8 + i  holds  P[kt*32 + (lane>>4)*8 + i][ct*16 + (lane&15)]
__global__ __launch_bounds__(256) void k_prep(const float* __restrict__ P,
                                              short* __restrict__ Pswz) {
    int idx = blockIdx.x * 256 + threadIdx.x;
    if (idx >= KTILES * 2 * 64 * 8) return;
    int i    = idx & 7;
    int lane = (idx >> 3) & 63;
    int rest = idx >> 9;
    int ct   = rest & 1;
    int kt   = rest >> 1;
    int k = kt * 32 + (lane >> 4) * 8 + i;
    int c = ct * 16 + (lane & 15);
    float v = (k < C_INN) ? P[k * RANK + c] : 0.0f;
    Pswz[idx] = f2bf(v);
}

// Y = x @ P via bf16 MFMA. Block = 4 waves; each wave: 16 rows x 32 cols, K=862.
__global__ __launch_bounds__(256) void k_encode_mfma(const float* __restrict__ x,
                                                     const short* __restrict__ Pswz,
                                                     float* __restrict__ Y) {
    int lane = threadIdx.x & 63;
    int wv   = threadIdx.x >> 6;
    long rowBase = (long)blockIdx.x * 64 + wv * 16;
    int mrow = lane & 15;
    int ksub = lane >> 4;
    const float* xr = x + (rowBase + mrow) * C_INN;
    const bf16x8* pb = (const bf16x8*)Pswz;
    f32x4 acc0 = {0.f, 0.f, 0.f, 0.f};
    f32x4 acc1 = {0.f, 0.f, 0.f, 0.f};

    for (int kt = 0; kt < KTILES - 1; ++kt) {
        int kbase = kt * 32 + ksub * 8;
        float2 u0 = *(const float2*)(xr + kbase);
        float2 u1 = *(const float2*)(xr + kbase + 2);
        float2 u2 = *(const float2*)(xr + kbase + 4);
        float2 u3 = *(const float2*)(xr + kbase + 6);
        bf16x8 a;
        a[0] = f2bf(u0.x); a[1] = f2bf(u0.y);
        a[2] = f2bf(u1.x); a[3] = f2bf(u1.y);
        a[4] = f2bf(u2.x); a[5] = f2bf(u2.y);
        a[6] = f2bf(u3.x); a[7] = f2bf(u3.y);
        bf16x8 b0 = pb[(kt * 2 + 0) * 64 + lane];
        bf16x8 b1 = pb[(kt * 2 + 1) * 64 + lane];
        acc0 = __builtin_amdgcn_mfma_f32_16x16x32_bf16(a, b0, acc0, 0, 0, 0);
        acc1 = __builtin_amdgcn_mfma_f32_16x16x32_bf16(a, b1, acc1, 0, 0, 0);
    }
    {   // tail: kt = 26, valid k = 832..861 (30 of 32); no OOB reads
        int kbase = 832 + ksub * 8;
        float vals[8];
        float2 u0 = *(const float2*)(xr + kbase);
        float2 u1 = *(const float2*)(xr + kbase + 2);
        float2 u2 = *(const float2*)(xr + kbase + 4);
        vals[0] = u0.x; vals[1] = u0.y;
        vals[2] = u1.x; vals[3] = u1.y;
        vals[4] = u2.x; vals[5] = u2.y;
        if (ksub < 3) {
            float2 u3 = *(const float2*)(xr + kbase + 6);
            vals[6] = u3.x; vals[7] = u3.y;
        } else {
            vals[6] = 0.f; vals[7] = 0.f;
        }
        bf16x8 a;
#pragma unroll
        for (int j = 0; j < 8; ++j) a[j] = f2bf(vals[j]);
        bf16x8 b0 = pb[(26 * 2 + 0) * 64 + lane];
        bf16x8 b1 = pb[(26 * 2 + 1) * 64 + lane];
        acc0 = __builtin_amdgcn_mfma_f32_16x16x32_bf16(a, b0, acc0, 0, 0, 0);
        acc1 = __builtin_amdgcn_mfma_f32_16x16x32_bf16(a, b1, acc1, 0, 0, 0);
    }
    // C/D layout (measured, guide §3): col = lane&15, row = (lane>>4)*4 + reg
    int cd_col   = lane & 15;
    int cd_rbase = (lane >> 4) * 4;
    float* y0 = Y + (rowBase + cd_rbase) * RANK;
#pragma unroll
    for (int j = 0; j < 4; ++j) {
        y0[j * RANK + cd_col]      = acc0[j];
        y0[j * RANK + 16 + cd_col] = acc1[j];
    }
}

// One block per batch b. Stats -> normalize -> DFT(48) -> complex mix -> iDFT(720) -> denorm.
__global__ __launch_bounds__(512) void k_freq(const float* __restrict__ Yg,
                                              float* __restrict__ Zg,
                                              const float2* __restrict__ ftab,
                                              const float2* __restrict__ itab,
                                              const float* __restrict__ Wr,
                                              const float* __restrict__ Wi,
                                              const float* __restrict__ brr,
                                              const float* __restrict__ bii) {
    __shared__ float Yb[T_SEQ * RANK];        // 92160 B
    __shared__ float Fre[FCUT * RANK];
    __shared__ float Fim[FCUT * RANK];
    __shared__ float Ore[GOUT * RANK];
    __shared__ float Oim[GOUT * RANK];
    __shared__ float red1[16 * 32];
    __shared__ float red2[16 * 32];
    __shared__ float meanS[RANK], stdS[RANK], istdS[RANK];

    int b   = blockIdx.x;
    int tid = threadIdx.x;
    const float* src = Yg + (size_t)b * T_SEQ * RANK;

    for (int i4 = tid; i4 < T_SEQ * RANK / 4; i4 += 512)
        ((float4*)Yb)[i4] = ((const float4*)src)[i4];
    __syncthreads();

    {
        int r = tid & 31, grp = tid >> 5;
        float s = 0.f, s2 = 0.f;
        for (int t = grp; t < T_SEQ; t += 16) {
            float v = Yb[t * RANK + r];
            s += v; s2 += v * v;
        }
        red1[grp * 32 + r] = s;
        red2[grp * 32 + r] = s2;
    }
    __syncthreads();
    if (tid < 32) {
        float s = 0.f, s2 = 0.f;
        for (int j = 0; j < 16; ++j) { s += red1[j * 32 + tid]; s2 += red2[j * 32 + tid]; }
        float mean = s / (float)T_SEQ;
        float var  = (s2 - (float)T_SEQ * mean * mean) / (float)(T_SEQ - 1);
        float sd   = sqrtf(var + 1e-5f);
        meanS[tid] = mean;
        stdS[tid]  = sd;
        istdS[tid] = 1.0f / sd;
    }
    __syncthreads();
    for (int e = tid; e < T_SEQ * RANK; e += 512) {
        int r = e & 31;
        Yb[e] = (Yb[e] - meanS[r]) * istdS[r];
    }
    __syncthreads();

    {
        int r2 = tid & 15, fg = tid >> 4;
        for (int f = fg; f < FCUT; f += 32) {
            float re0 = 0.f, im0 = 0.f, re1 = 0.f, im1 = 0.f;
            const float2* ft = ftab + f * T_SEQ;
#pragma unroll 4
            for (int t = 0; t < T_SEQ; ++t) {
                float2 y  = *(const float2*)(Yb + t * RANK + 2 * r2);
                float2 cs = ft[t];
                re0 += y.x * cs.x;  im0 -= y.x * cs.y;
                re1 += y.y * cs.x;  im1 -= y.y * cs.y;
            }
            Fre[f * RANK + 2 * r2]     = re0;
            Fre[f * RANK + 2 * r2 + 1] = re1;
            Fim[f * RANK + 2 * r2]     = im0;
            Fim[f * RANK + 2 * r2 + 1] = im1;
        }
    }
    __syncthreads();

    {
        int r = tid & 31, gg = tid >> 5;
        for (int g = gg; g < GOUT; g += 16) {
            float are = brr[r * GOUT + g];
            float aim = bii[r * GOUT + g];
            const float* wr = Wr + ((size_t)r * GOUT + g) * FCUT;
            const float* wi = Wi + ((size_t)r * GOUT + g) * FCUT;
#pragma unroll 4
            for (int f = 0; f < FCUT; ++f) {
                float fr = Fre[f * RANK + r], fi = Fim[f * RANK + r];
                float wrv = wr[f], wiv = wi[f];
                are += fr * wrv - fi * wiv;
                aim += fr * wiv + fi * wrv;
            }
            Ore[g * RANK + r] = are;
            Oim[g * RANK + r] = aim;
        }
    }
    __syncthreads();

    {
        int r2 = tid & 15, tg = tid >> 4;
        float m0  = meanS[2 * r2],  m1  = meanS[2 * r2 + 1];
        float sd0 = stdS[2 * r2],   sd1 = stdS[2 * r2 + 1];
        float dc0 = Ore[2 * r2],    dc1 = Ore[2 * r2 + 1];
        for (int tl = tg; tl < T_SEQ; tl += 32) {
            float s0 = 0.f, s1 = 0.f;
            const float2* it = itab + tl * GOUT;
#pragma unroll 4
            for (int g = 1; g < GOUT; ++g) {
                float2 cs  = it[g];
                float2 ore = *(const float2*)(Ore + g * RANK + 2 * r2);
                float2 oim = *(const float2*)(Oim + g * RANK + 2 * r2);
                s0 += ore.x * cs.x - oim.x * cs.y;
                s1 += ore.y * cs.x - oim.y * cs.y;
            }
            float v0 = (dc0 + 2.0f * s0) * (1.0f / 720.0f);
            float v1 = (dc1 + 2.0f * s1) * (1.0f / 720.0f);
            v0 = v0 * sd0 + m0;
            v1 = v1 * sd1 + m1;
            *(float2*)(Zg + (size_t)b * T_SEQ * RANK + tl * RANK + 2 * r2) = make_float2(v0, v1);
        }
    }
}

__global__ __launch_bounds__(256) void k_decode(const float* __restrict__ Z,
                                                const float* __restrict__ D,
                                                float* __restrict__ out) {
    int tid = threadIdx.x;
    int c0 = tid, c1 = tid + 256, c2 = tid + 512, c3 = tid + 768;
    bool v3 = (c3 < C_INN);
    float d0[RANK], d1[RANK], d2[RANK], d3[RANK];
#pragma unroll
    for (int k = 0; k < RANK; ++k) {
        d0[k] = D[k * C_INN + c0];
        d1[k] = D[k * C_INN + c1];
        d2[k] = D[k * C_INN + c2];
        d3[k] = v3 ? D[k * C_INN + c3] : 0.f;
    }
    long rowBase = (long)blockIdx.x * 128;
    for (int i = 0; i < 128; ++i) {
        long row = rowBase + i;
        const float* z = Z + row * RANK;
        float a0 = 0.f, a1 = 0.f, a2 = 0.f, a3 = 0.f;
#pragma unroll
        for (int k = 0; k < RANK; ++k) {
            float zv = z[k];
            a0 += zv * d0[k];
            a1 += zv * d1[k];
            a2 += zv * d2[k];
            a3 += zv * d3[k];
        }
        float* o = out + row * C_INN;
        o[c0] = a0;
        o[c1] = a1;
        o[c2] = a2;
        if (v3) o[c3] = a3;
    }
}

extern "C" void kernel_launch(void* const* d_in, const int* in_sizes, int n_in,
                              void* d_out, int out_size, void* d_ws, size_t ws_size,
                              hipStream_t stream) {
    const float* x   = (const float*)d_in[0];
    const float* P   = (const float*)d_in[1];
    const float* D   = (const float*)d_in[2];
    const float* Wr  = (const float*)d_in[3];
    const float* Wi  = (const float*)d_in[4];
    const float* brr = (const float*)d_in[5];
    const float* bii = (const float*)d_in[6];
    float* out = (float*)d_out;
    float* ws  = (float*)d_ws;

    float*  Y    = ws;
    float2* ftab = (float2*)(ws + FTAB_OFF);
    float2* itab = (float2*)(ws + ITAB_OFF);
    short*  Pswz = (short*)(ws + PSWZ_OFF);

    k_tabgen<<<405, 256, 0, stream>>>(ftab, itab);
    k_prep<<<(KTILES * 2 * 64 * 8 + 255) / 256, 256, 0, stream>>>(P, Pswz);
    k_encode_mfma<<<(B_SZ * T_SEQ) / 64, 256, 0, stream>>>(x, Pswz, Y);   // 2880 blocks
    k_freq<<<B_SZ, 512, 0, stream>>>(Y, Y, ftab, itab, Wr, Wi, brr, bii);
    k_decode<<<(B_SZ * T_SEQ) / 128, 256, 0, stream>>>(Y, D, out);
}

// Round 3
// 487.385 us; speedup vs baseline: 3.6368x; 1.5693x over previous
//
#include <hip/hip_runtime.h>
#include <math.h>

#define B_SZ   256
#define T_SEQ  720
#define C_INN  862
#define RANK   32
#define FCUT   48
#define GOUT   96
#define KTILES 27            // ceil(862/32) for encode

// ws layout (floats):
// [0, 5898240)            Y buffer (B*T*RANK)
// [5898240, 5912064)      Pswz : 27648 bf16 shorts (encode B-frags)
// [5912064, 5947392)      ftabB: 70656 bf16 shorts (fwd-DFT A-frags, 96x736)
// [5947392, 6016512)      itabB: 138240 bf16 shorts (iDFT A-frags, 720x192)
#define PSWZ_OFF  (5898240)
#define FTABB_OFF (5912064)
#define ITABB_OFF (5947392)

typedef __attribute__((ext_vector_type(8))) short bf16x8;
typedef __attribute__((ext_vector_type(4))) float f32x4;

__device__ inline short f2bf(float f) {
    union { float f; unsigned u; } v; v.f = f;
    unsigned r = (v.u + 0x7fffu + ((v.u >> 16) & 1u)) >> 16;   // RNE
    return (short)r;
}

// One kernel fills all three precomputed tables. 924*256 == 138240+70656+27648.
__global__ __launch_bounds__(256) void k_prep_all(const float* __restrict__ P,
                                                  short* __restrict__ Pswz,
                                                  short* __restrict__ ftabB,
                                                  short* __restrict__ itabB) {
    int idx = blockIdx.x * 256 + threadIdx.x;
    const float TWO_PI = 6.28318530717958647692f;
    if (idx < 138240) {
        // iDFT A-table: A[t][k], t=0..719 (M=45 tiles), k=0..191 (6 K-steps)
        // A[t][0]=0.5, A[t][1]=0; A[t][2g]=cos(2*pi*g*(720+t)/1440), A[t][2g+1]=sin(...)
        int i = idx & 7, l = (idx >> 3) & 63, rest = idx >> 9;
        int ks = rest % 6, mt = rest / 6;
        int t = mt * 16 + (l & 15);
        int k = ks * 32 + ((l >> 4) << 3) + i;
        int g = k >> 1, odd = k & 1;
        float val;
        if (g == 0) {
            val = odd ? 0.0f : 0.5f;
        } else {
            int m = (g * (720 + t)) % 1440;
            float th = TWO_PI * (float)m * (1.0f / 1440.0f);
            val = odd ? sinf(th) : cosf(th);
        }
        itabB[idx] = f2bf(val);
    } else if (idx < 138240 + 70656) {
        // fwd-DFT A-table: A[row][t], row=0..95 (row2f=cos, 2f+1=-sin), t=0..735 (23 K-steps)
        int j = idx - 138240;
        int i = j & 7, l = (j >> 3) & 63, rest = j >> 9;
        int ks = rest % 23, mt = rest / 23;
        int row = mt * 16 + (l & 15);
        int t = ks * 32 + ((l >> 4) << 3) + i;
        int f = row >> 1, odd = row & 1;
        float val = 0.0f;
        if (t < T_SEQ) {
            int m = (f * t) % T_SEQ;
            float th = TWO_PI * (float)m * (1.0f / 720.0f);
            val = odd ? -sinf(th) : cosf(th);
        }
        ftabB[j] = f2bf(val);
    } else {
        // encode B-frags (as round 2, verified)
        int j = idx - 138240 - 70656;
        int i = j & 7, lane = (j >> 3) & 63, rest = j >> 9;
        int ct = rest & 1, kt = rest >> 1;
        int k = kt * 32 + ((lane >> 4) << 3) + i;
        int c = ct * 16 + (lane & 15);
        float v = (k < C_INN) ? P[k * RANK + c] : 0.0f;
        Pswz[j] = f2bf(v);
    }
}

// Y = x @ P via bf16 MFMA (unchanged from round 2, verified).
__global__ __launch_bounds__(256) void k_encode_mfma(const float* __restrict__ x,
                                                     const short* __restrict__ Pswz,
                                                     float* __restrict__ Y) {
    int lane = threadIdx.x & 63;
    int wv   = threadIdx.x >> 6;
    long rowBase = (long)blockIdx.x * 64 + wv * 16;
    int mrow = lane & 15;
    int ksub = lane >> 4;
    const float* xr = x + (rowBase + mrow) * C_INN;
    const bf16x8* pb = (const bf16x8*)Pswz;
    f32x4 acc0 = {0.f, 0.f, 0.f, 0.f};
    f32x4 acc1 = {0.f, 0.f, 0.f, 0.f};

    for (int kt = 0; kt < KTILES - 1; ++kt) {
        int kbase = kt * 32 + ksub * 8;
        float2 u0 = *(const float2*)(xr + kbase);
        float2 u1 = *(const float2*)(xr + kbase + 2);
        float2 u2 = *(const float2*)(xr + kbase + 4);
        float2 u3 = *(const float2*)(xr + kbase + 6);
        bf16x8 a;
        a[0] = f2bf(u0.x); a[1] = f2bf(u0.y);
        a[2] = f2bf(u1.x); a[3] = f2bf(u1.y);
        a[4] = f2bf(u2.x); a[5] = f2bf(u2.y);
        a[6] = f2bf(u3.x); a[7] = f2bf(u3.y);
        bf16x8 b0 = pb[(kt * 2 + 0) * 64 + lane];
        bf16x8 b1 = pb[(kt * 2 + 1) * 64 + lane];
        acc0 = __builtin_amdgcn_mfma_f32_16x16x32_bf16(a, b0, acc0, 0, 0, 0);
        acc1 = __builtin_amdgcn_mfma_f32_16x16x32_bf16(a, b1, acc1, 0, 0, 0);
    }
    {   // tail: kt = 26, valid k = 832..861
        int kbase = 832 + ksub * 8;
        float vals[8];
        float2 u0 = *(const float2*)(xr + kbase);
        float2 u1 = *(const float2*)(xr + kbase + 2);
        float2 u2 = *(const float2*)(xr + kbase + 4);
        vals[0] = u0.x; vals[1] = u0.y;
        vals[2] = u1.x; vals[3] = u1.y;
        vals[4] = u2.x; vals[5] = u2.y;
        if (ksub < 3) {
            float2 u3 = *(const float2*)(xr + kbase + 6);
            vals[6] = u3.x; vals[7] = u3.y;
        } else {
            vals[6] = 0.f; vals[7] = 0.f;
        }
        bf16x8 a;
#pragma unroll
        for (int j = 0; j < 8; ++j) a[j] = f2bf(vals[j]);
        bf16x8 b0 = pb[(26 * 2 + 0) * 64 + lane];
        bf16x8 b1 = pb[(26 * 2 + 1) * 64 + lane];
        acc0 = __builtin_amdgcn_mfma_f32_16x16x32_bf16(a, b0, acc0, 0, 0, 0);
        acc1 = __builtin_amdgcn_mfma_f32_16x16x32_bf16(a, b1, acc1, 0, 0, 0);
    }
    int cd_col   = lane & 15;
    int cd_rbase = (lane >> 4) * 4;
    float* y0 = Y + (rowBase + cd_rbase) * RANK;
#pragma unroll
    for (int j = 0; j < 4; ++j) {
        y0[j * RANK + cd_col]      = acc0[j];
        y0[j * RANK + 16 + cd_col] = acc1[j];
    }
}

// Fused per-batch: stats -> normalize -> fwdDFT(MFMA) -> mix -> iDFT(MFMA) -> decode(f32) -> out
__global__ __launch_bounds__(1024) void k_fused(const float* __restrict__ Yg,
                                                const short* __restrict__ ftabB,
                                                const short* __restrict__ itabB,
                                                const float* __restrict__ Wr,
                                                const float* __restrict__ Wi,
                                                const float* __restrict__ brr,
                                                const float* __restrict__ bii,
                                                const float* __restrict__ Dg,
                                                float* __restrict__ out) {
    __shared__ float Yb[736 * 32];       // 94208 B (rows 720..735 zero)
    __shared__ float Fre[FCUT * 32];     // 6144
    __shared__ float Fim[FCUT * 32];     // 6144
    __shared__ short OB[6144];           // 12288 B  iDFT B-frags (192x32 bf16)
    __shared__ float red1[32 * 32];      // 4096
    __shared__ float red2[32 * 32];      // 4096
    __shared__ float meanS[32], stdS[32], istdS[32];

    int b   = blockIdx.x;
    int tid = threadIdx.x;
    int l   = tid & 63;
    int w   = tid >> 6;                  // wave 0..15
    const float* src = Yg + (size_t)b * T_SEQ * RANK;

    // ---- load + zero tail rows ----
    for (int i4 = tid; i4 < 5888; i4 += 1024) {
        float4 v = (i4 < 5760) ? ((const float4*)src)[i4] : make_float4(0.f, 0.f, 0.f, 0.f);
        ((float4*)Yb)[i4] = v;
    }
    __syncthreads();

    // ---- stats ----
    {
        int r = tid & 31, grp = tid >> 5;
        float s = 0.f, s2 = 0.f;
        for (int t = grp; t < T_SEQ; t += 32) {
            float v = Yb[t * 32 + r];
            s += v; s2 += v * v;
        }
        red1[grp * 32 + r] = s;
        red2[grp * 32 + r] = s2;
    }
    __syncthreads();
    if (tid < 32) {
        float s = 0.f, s2 = 0.f;
        for (int j = 0; j < 32; ++j) { s += red1[j * 32 + tid]; s2 += red2[j * 32 + tid]; }
        float mean = s / 720.0f;
        float var  = (s2 - 720.0f * mean * mean) / 719.0f;
        float sd   = sqrtf(var + 1e-5f);
        meanS[tid] = mean;
        stdS[tid]  = sd;
        istdS[tid] = 1.0f / sd;
    }
    __syncthreads();

    // ---- normalize (rows < 720; tail stays zero) ----
    for (int e = tid; e < T_SEQ * 32; e += 1024) {
        int r = e & 31;
        Yb[e] = (Yb[e] - meanS[r]) * istdS[r];
    }
    __syncthreads();

    // ---- forward DFT via MFMA: F_all(96x32) = ftab(96x736) @ Yn(736x32); waves 0..11 ----
    if (w < 12) {
        int mt = w >> 1, ct = w & 1;
        int cc = ct * 16 + (l & 15);
        int khalf = (l >> 4) * 8;
        f32x4 acc = {0.f, 0.f, 0.f, 0.f};
        for (int ks = 0; ks < 23; ++ks) {
            bf16x8 a = ((const bf16x8*)ftabB)[(mt * 23 + ks) * 64 + l];
            int kb = ks * 32 + khalf;
            bf16x8 bb;
#pragma unroll
            for (int i = 0; i < 8; ++i) bb[i] = f2bf(Yb[(kb + i) * 32 + cc]);
            acc = __builtin_amdgcn_mfma_f32_16x16x32_bf16(a, bb, acc, 0, 0, 0);
        }
        int rowb = mt * 16 + (l >> 4) * 4;
#pragma unroll
        for (int j = 0; j < 4; ++j) {
            int row = rowb + j;
            int f = row >> 1;
            if (row & 1) Fim[f * 32 + cc] = acc[j];
            else         Fre[f * 32 + cc] = acc[j];
        }
    }
    __syncthreads();

    // ---- mix: O[g][r] = sum_f F[f][r]*W[r][g][f] + b[r][g]; write into OB B-frag layout ----
    {
        int r = tid & 31, gg = tid >> 5;
        for (int g = gg; g < GOUT; g += 32) {
            float are = brr[r * GOUT + g];
            float aim = bii[r * GOUT + g];
            const float4* wr4 = (const float4*)(Wr + ((size_t)r * GOUT + g) * FCUT);
            const float4* wi4 = (const float4*)(Wi + ((size_t)r * GOUT + g) * FCUT);
#pragma unroll 3
            for (int q = 0; q < 12; ++q) {
                float4 wr = wr4[q], wi = wi4[q];
                int f0 = q * 4;
                float fr, fi;
                fr = Fre[(f0 + 0) * 32 + r]; fi = Fim[(f0 + 0) * 32 + r];
                are += fr * wr.x - fi * wi.x;  aim += fr * wi.x + fi * wr.x;
                fr = Fre[(f0 + 1) * 32 + r]; fi = Fim[(f0 + 1) * 32 + r];
                are += fr * wr.y - fi * wi.y;  aim += fr * wi.y + fi * wr.y;
                fr = Fre[(f0 + 2) * 32 + r]; fi = Fim[(f0 + 2) * 32 + r];
                are += fr * wr.z - fi * wi.z;  aim += fr * wi.z + fi * wr.z;
                fr = Fre[(f0 + 3) * 32 + r]; fi = Fim[(f0 + 3) * 32 + r];
                are += fr * wr.w - fi * wi.w;  aim += fr * wi.w + fi * wr.w;
            }
            // B[2g][r] = Ore, B[2g+1][r] = -Oim ; pack two consecutive shorts -> one u32
            int ks   = g >> 4;
            int kk   = (2 * g) & 31;          // even
            int lane = (kk >> 3) * 16 + (r & 15);
            int ct   = r >> 4;
            unsigned lo = (unsigned short)f2bf(are);
            unsigned hi = (unsigned short)f2bf(-aim);
            ((unsigned*)OB)[((((ks * 2 + ct) * 64 + lane) * 8) + (kk & 7)) >> 1] = lo | (hi << 16);
        }
    }
    __syncthreads();

    // ---- iDFT via MFMA: z(720x32) = itab(720x192) @ OB(192x32); denorm; z -> Yb ----
    for (int mt = w; mt < 45; mt += 16) {
        f32x4 acc0 = {0.f, 0.f, 0.f, 0.f};
        f32x4 acc1 = {0.f, 0.f, 0.f, 0.f};
#pragma unroll
        for (int ks = 0; ks < 6; ++ks) {
            bf16x8 a  = ((const bf16x8*)itabB)[(mt * 6 + ks) * 64 + l];
            bf16x8 b0 = *(const bf16x8*)&OB[((ks * 2 + 0) * 64 + l) * 8];
            bf16x8 b1 = *(const bf16x8*)&OB[((ks * 2 + 1) * 64 + l) * 8];
            acc0 = __builtin_amdgcn_mfma_f32_16x16x32_bf16(a, b0, acc0, 0, 0, 0);
            acc1 = __builtin_amdgcn_mfma_f32_16x16x32_bf16(a, b1, acc1, 0, 0, 0);
        }
        int c0 = l & 15, c1 = 16 + (l & 15);
        int rb = (l >> 4) * 4;
        float m0 = meanS[c0], sd0 = stdS[c0];
        float m1 = meanS[c1], sd1 = stdS[c1];
#pragma unroll
        for (int j = 0; j < 4; ++j) {
            int t = mt * 16 + rb + j;
            Yb[t * 32 + c0] = acc0[j] * (1.0f / 360.0f) * sd0 + m0;
            Yb[t * 32 + c1] = acc1[j] * (1.0f / 360.0f) * sd1 + m1;
        }
    }
    __syncthreads();

    // ---- decode fp32: out[t][c] = sum_k z[t][k] * D[k][c]; wave w owns t in [45w, 45w+45) ----
    {
        int t0 = w * 45;
        float* outb = out + (size_t)b * T_SEQ * C_INN;
        for (int pass = 0; pass < 7; ++pass) {
            int c = pass * 128 + 2 * l;
            bool valid = (c < C_INN);
            int cl = valid ? c : 0;
            float2 dreg[32];
#pragma unroll
            for (int k = 0; k < 32; ++k)
                dreg[k] = *(const float2*)(Dg + k * C_INN + cl);
            for (int tt = 0; tt < 45; ++tt) {
                int t = t0 + tt;
                const float* zr = &Yb[t * 32];
                float a0 = 0.f, a1 = 0.f;
#pragma unroll
                for (int kq = 0; kq < 8; ++kq) {
                    float4 z4 = *(const float4*)(zr + kq * 4);
                    a0 += z4.x * dreg[kq * 4 + 0].x;  a1 += z4.x * dreg[kq * 4 + 0].y;
                    a0 += z4.y * dreg[kq * 4 + 1].x;  a1 += z4.y * dreg[kq * 4 + 1].y;
                    a0 += z4.z * dreg[kq * 4 + 2].x;  a1 += z4.z * dreg[kq * 4 + 2].y;
                    a0 += z4.w * dreg[kq * 4 + 3].x;  a1 += z4.w * dreg[kq * 4 + 3].y;
                }
                if (valid) *(float2*)(outb + (size_t)t * C_INN + c) = make_float2(a0, a1);
            }
        }
    }
}

extern "C" void kernel_launch(void* const* d_in, const int* in_sizes, int n_in,
                              void* d_out, int out_size, void* d_ws, size_t ws_size,
                              hipStream_t stream) {
    const float* x   = (const float*)d_in[0];
    const float* P   = (const float*)d_in[1];
    const float* D   = (const float*)d_in[2];
    const float* Wr  = (const float*)d_in[3];
    const float* Wi  = (const float*)d_in[4];
    const float* brr = (const float*)d_in[5];
    const float* bii = (const float*)d_in[6];
    float* out = (float*)d_out;
    float* ws  = (float*)d_ws;

    float* Y     = ws;
    short* Pswz  = (short*)(ws + PSWZ_OFF);
    short* ftabB = (short*)(ws + FTABB_OFF);
    short* itabB = (short*)(ws + ITABB_OFF);

    k_prep_all<<<924, 256, 0, stream>>>(P, Pswz, ftabB, itabB);
    k_encode_mfma<<<(B_SZ * T_SEQ) / 64, 256, 0, stream>>>(x, Pswz, Y);   // 2880 blocks
    k_fused<<<B_SZ, 1024, 0, stream>>>(Y, ftabB, itabB, Wr, Wi, brr, bii, D, out);
}

// Round 4
// 429.483 us; speedup vs baseline: 4.1271x; 1.1348x over previous
//
#include <hip/hip_runtime.h>
#include <math.h>

#define B_SZ   256
#define T_SEQ  720
#define C_INN  862
#define RANK   32
#define FCUT   48
#define GOUT   96
#define KTILES 27            // ceil(862/32) for encode

// ws layout (float offsets):
// [0, 5898240)            Y buffer (B*T*RANK)
// [5898240, 5912064)      Pswz : 27648 bf16 shorts (encode B-frags)
// [5912064, 5947392)      ftabB: 70656 bf16 shorts (fwd-DFT A-frags, 96x736)
// [5947392, 6016512)      itabB: 138240 bf16 shorts (iDFT A-frags, 720x192)
// [6016512, 6030336)      Dswz : 27648 bf16 shorts (decode B-frags, 32x864)
#define PSWZ_OFF  (5898240)
#define FTABB_OFF (5912064)
#define ITABB_OFF (5947392)
#define DSWZ_OFF  (6016512)

typedef __attribute__((ext_vector_type(8))) short bf16x8;
typedef __attribute__((ext_vector_type(4))) float f32x4;

__device__ inline short f2bf(float f) {
    union { float f; unsigned u; } v; v.f = f;
    unsigned r = (v.u + 0x7fffu + ((v.u >> 16) & 1u)) >> 16;   // RNE
    return (short)r;
}

// Fills all four precomputed tables. 1032*256 == 138240+70656+27648+27648.
__global__ __launch_bounds__(256) void k_prep_all(const float* __restrict__ P,
                                                  const float* __restrict__ D,
                                                  short* __restrict__ Pswz,
                                                  short* __restrict__ ftabB,
                                                  short* __restrict__ itabB,
                                                  short* __restrict__ Dswz) {
    int idx = blockIdx.x * 256 + threadIdx.x;
    const float TWO_PI = 6.28318530717958647692f;
    if (idx < 138240) {
        // iDFT A-table: A[t][k], t tiles of 16 (45), k=0..191 (6 K-steps)
        int i = idx & 7, l = (idx >> 3) & 63, rest = idx >> 9;
        int ks = rest % 6, mt = rest / 6;
        int t = mt * 16 + (l & 15);
        int k = ks * 32 + ((l >> 4) << 3) + i;
        int g = k >> 1, odd = k & 1;
        float val;
        if (g == 0) {
            val = odd ? 0.0f : 0.5f;
        } else {
            int m = (g * (720 + t)) % 1440;
            float th = TWO_PI * (float)m * (1.0f / 1440.0f);
            val = odd ? sinf(th) : cosf(th);
        }
        itabB[idx] = f2bf(val);
    } else if (idx < 138240 + 70656) {
        // fwd-DFT A-table: A[row][t], row 2f=cos / 2f+1=-sin, t=0..735 (23 K-steps)
        int j = idx - 138240;
        int i = j & 7, l = (j >> 3) & 63, rest = j >> 9;
        int ks = rest % 23, mt = rest / 23;
        int row = mt * 16 + (l & 15);
        int t = ks * 32 + ((l >> 4) << 3) + i;
        int f = row >> 1, odd = row & 1;
        float val = 0.0f;
        if (t < T_SEQ) {
            int m = (f * t) % T_SEQ;
            float th = TWO_PI * (float)m * (1.0f / 720.0f);
            val = odd ? -sinf(th) : cosf(th);
        }
        ftabB[j] = f2bf(val);
    } else if (idx < 138240 + 70656 + 27648) {
        // encode B-frags (verified round 2)
        int j = idx - 138240 - 70656;
        int i = j & 7, lane = (j >> 3) & 63, rest = j >> 9;
        int ct = rest & 1, kt = rest >> 1;
        int k = kt * 32 + ((lane >> 4) << 3) + i;
        int c = ct * 16 + (lane & 15);
        float v = (k < C_INN) ? P[k * RANK + c] : 0.0f;
        Pswz[j] = f2bf(v);
    } else {
        // decode B-frags: tile ct in [0,54), B[k][c] = D[k][ct*16 + (l&15)], k=(l>>4)*8+i
        int j = idx - 138240 - 70656 - 27648;
        int i = j & 7, lane = (j >> 3) & 63, ct = j >> 9;
        int k = ((lane >> 4) << 3) + i;
        int c = ct * 16 + (lane & 15);
        float v = (c < C_INN) ? D[k * C_INN + c] : 0.0f;
        Dswz[j] = f2bf(v);
    }
}

// Y = x @ P via bf16 MFMA (unchanged, verified).
__global__ __launch_bounds__(256) void k_encode_mfma(const float* __restrict__ x,
                                                     const short* __restrict__ Pswz,
                                                     float* __restrict__ Y) {
    int lane = threadIdx.x & 63;
    int wv   = threadIdx.x >> 6;
    long rowBase = (long)blockIdx.x * 64 + wv * 16;
    int mrow = lane & 15;
    int ksub = lane >> 4;
    const float* xr = x + (rowBase + mrow) * C_INN;
    const bf16x8* pb = (const bf16x8*)Pswz;
    f32x4 acc0 = {0.f, 0.f, 0.f, 0.f};
    f32x4 acc1 = {0.f, 0.f, 0.f, 0.f};

    for (int kt = 0; kt < KTILES - 1; ++kt) {
        int kbase = kt * 32 + ksub * 8;
        float2 u0 = *(const float2*)(xr + kbase);
        float2 u1 = *(const float2*)(xr + kbase + 2);
        float2 u2 = *(const float2*)(xr + kbase + 4);
        float2 u3 = *(const float2*)(xr + kbase + 6);
        bf16x8 a;
        a[0] = f2bf(u0.x); a[1] = f2bf(u0.y);
        a[2] = f2bf(u1.x); a[3] = f2bf(u1.y);
        a[4] = f2bf(u2.x); a[5] = f2bf(u2.y);
        a[6] = f2bf(u3.x); a[7] = f2bf(u3.y);
        bf16x8 b0 = pb[(kt * 2 + 0) * 64 + lane];
        bf16x8 b1 = pb[(kt * 2 + 1) * 64 + lane];
        acc0 = __builtin_amdgcn_mfma_f32_16x16x32_bf16(a, b0, acc0, 0, 0, 0);
        acc1 = __builtin_amdgcn_mfma_f32_16x16x32_bf16(a, b1, acc1, 0, 0, 0);
    }
    {   // tail: kt = 26, valid k = 832..861
        int kbase = 832 + ksub * 8;
        float vals[8];
        float2 u0 = *(const float2*)(xr + kbase);
        float2 u1 = *(const float2*)(xr + kbase + 2);
        float2 u2 = *(const float2*)(xr + kbase + 4);
        vals[0] = u0.x; vals[1] = u0.y;
        vals[2] = u1.x; vals[3] = u1.y;
        vals[4] = u2.x; vals[5] = u2.y;
        if (ksub < 3) {
            float2 u3 = *(const float2*)(xr + kbase + 6);
            vals[6] = u3.x; vals[7] = u3.y;
        } else {
            vals[6] = 0.f; vals[7] = 0.f;
        }
        bf16x8 a;
#pragma unroll
        for (int j = 0; j < 8; ++j) a[j] = f2bf(vals[j]);
        bf16x8 b0 = pb[(26 * 2 + 0) * 64 + lane];
        bf16x8 b1 = pb[(26 * 2 + 1) * 64 + lane];
        acc0 = __builtin_amdgcn_mfma_f32_16x16x32_bf16(a, b0, acc0, 0, 0, 0);
        acc1 = __builtin_amdgcn_mfma_f32_16x16x32_bf16(a, b1, acc1, 0, 0, 0);
    }
    int cd_col   = lane & 15;
    int cd_rbase = (lane >> 4) * 4;
    float* y0 = Y + (rowBase + cd_rbase) * RANK;
#pragma unroll
    for (int j = 0; j < 4; ++j) {
        y0[j * RANK + cd_col]      = acc0[j];
        y0[j * RANK + 16 + cd_col] = acc1[j];
    }
}

// Fused per-batch: stats -> normalize -> fwdDFT(MFMA) -> mix -> iDFT(MFMA) -> decode(MFMA) -> out
__global__ __launch_bounds__(1024) void k_fused(const float* __restrict__ Yg,
                                                const short* __restrict__ ftabB,
                                                const short* __restrict__ itabB,
                                                const short* __restrict__ Dswz,
                                                const float* __restrict__ Wr,
                                                const float* __restrict__ Wi,
                                                const float* __restrict__ brr,
                                                const float* __restrict__ bii,
                                                float* __restrict__ out) {
    __shared__ float Yb[736 * 32];       // 94208 B (rows 720..735 zero)
    __shared__ float Fre[FCUT * 32];
    __shared__ float Fim[FCUT * 32];
    __shared__ short OB[6144];           // iDFT B-frags (192x32 bf16)
    __shared__ float red1[32 * 32];
    __shared__ float red2[32 * 32];
    __shared__ float meanS[32], stdS[32], istdS[32];

    int b   = blockIdx.x;
    int tid = threadIdx.x;
    int l   = tid & 63;
    int w   = tid >> 6;                  // wave 0..15
    const float* src = Yg + (size_t)b * T_SEQ * RANK;

    // ---- load + zero tail rows ----
    for (int i4 = tid; i4 < 5888; i4 += 1024) {
        float4 v = (i4 < 5760) ? ((const float4*)src)[i4] : make_float4(0.f, 0.f, 0.f, 0.f);
        ((float4*)Yb)[i4] = v;
    }
    __syncthreads();

    // ---- stats ----
    {
        int r = tid & 31, grp = tid >> 5;
        float s = 0.f, s2 = 0.f;
        for (int t = grp; t < T_SEQ; t += 32) {
            float v = Yb[t * 32 + r];
            s += v; s2 += v * v;
        }
        red1[grp * 32 + r] = s;
        red2[grp * 32 + r] = s2;
    }
    __syncthreads();
    if (tid < 32) {
        float s = 0.f, s2 = 0.f;
        for (int j = 0; j < 32; ++j) { s += red1[j * 32 + tid]; s2 += red2[j * 32 + tid]; }
        float mean = s / 720.0f;
        float var  = (s2 - 720.0f * mean * mean) / 719.0f;
        float sd   = sqrtf(var + 1e-5f);
        meanS[tid] = mean;
        stdS[tid]  = sd;
        istdS[tid] = 1.0f / sd;
    }
    __syncthreads();

    // ---- normalize ----
    for (int e = tid; e < T_SEQ * 32; e += 1024) {
        int r = e & 31;
        Yb[e] = (Yb[e] - meanS[r]) * istdS[r];
    }
    __syncthreads();

    // ---- forward DFT via MFMA: F_all(96x32) = ftab(96x736) @ Yn(736x32); waves 0..11 ----
    if (w < 12) {
        int mt = w >> 1, ct = w & 1;
        int cc = ct * 16 + (l & 15);
        int khalf = (l >> 4) * 8;
        f32x4 acc = {0.f, 0.f, 0.f, 0.f};
        for (int ks = 0; ks < 23; ++ks) {
            bf16x8 a = ((const bf16x8*)ftabB)[(mt * 23 + ks) * 64 + l];
            int kb = ks * 32 + khalf;
            bf16x8 bb;
#pragma unroll
            for (int i = 0; i < 8; ++i) bb[i] = f2bf(Yb[(kb + i) * 32 + cc]);
            acc = __builtin_amdgcn_mfma_f32_16x16x32_bf16(a, bb, acc, 0, 0, 0);
        }
        int rowb = mt * 16 + (l >> 4) * 4;
#pragma unroll
        for (int j = 0; j < 4; ++j) {
            int row = rowb + j;
            int f = row >> 1;
            if (row & 1) Fim[f * 32 + cc] = acc[j];
            else         Fre[f * 32 + cc] = acc[j];
        }
    }
    __syncthreads();

    // ---- mix: O[g][r] = sum_f F[f][r]*W[r][g][f] + b[r][g]; write into OB B-frag layout ----
    {
        int r = tid & 31, gg = tid >> 5;
        for (int g = gg; g < GOUT; g += 32) {
            float are = brr[r * GOUT + g];
            float aim = bii[r * GOUT + g];
            const float4* wr4 = (const float4*)(Wr + ((size_t)r * GOUT + g) * FCUT);
            const float4* wi4 = (const float4*)(Wi + ((size_t)r * GOUT + g) * FCUT);
#pragma unroll 3
            for (int q = 0; q < 12; ++q) {
                float4 wr = wr4[q], wi = wi4[q];
                int f0 = q * 4;
                float fr, fi;
                fr = Fre[(f0 + 0) * 32 + r]; fi = Fim[(f0 + 0) * 32 + r];
                are += fr * wr.x - fi * wi.x;  aim += fr * wi.x + fi * wr.x;
                fr = Fre[(f0 + 1) * 32 + r]; fi = Fim[(f0 + 1) * 32 + r];
                are += fr * wr.y - fi * wi.y;  aim += fr * wi.y + fi * wr.y;
                fr = Fre[(f0 + 2) * 32 + r]; fi = Fim[(f0 + 2) * 32 + r];
                are += fr * wr.z - fi * wi.z;  aim += fr * wi.z + fi * wr.z;
                fr = Fre[(f0 + 3) * 32 + r]; fi = Fim[(f0 + 3) * 32 + r];
                are += fr * wr.w - fi * wi.w;  aim += fr * wi.w + fi * wr.w;
            }
            int ks   = g >> 4;
            int kk   = (2 * g) & 31;          // even
            int lane = (kk >> 3) * 16 + (r & 15);
            int ct   = r >> 4;
            unsigned lo = (unsigned short)f2bf(are);
            unsigned hi = (unsigned short)f2bf(-aim);
            ((unsigned*)OB)[((((ks * 2 + ct) * 64 + lane) * 8) + (kk & 7)) >> 1] = lo | (hi << 16);
        }
    }
    __syncthreads();

    // ---- iDFT via MFMA: z(720x32) = itab(720x192) @ OB(192x32); denorm; z -> Yb ----
    for (int mt = w; mt < 45; mt += 16) {
        f32x4 acc0 = {0.f, 0.f, 0.f, 0.f};
        f32x4 acc1 = {0.f, 0.f, 0.f, 0.f};
#pragma unroll
        for (int ks = 0; ks < 6; ++ks) {
            bf16x8 a  = ((const bf16x8*)itabB)[(mt * 6 + ks) * 64 + l];
            bf16x8 b0 = *(const bf16x8*)&OB[((ks * 2 + 0) * 64 + l) * 8];
            bf16x8 b1 = *(const bf16x8*)&OB[((ks * 2 + 1) * 64 + l) * 8];
            acc0 = __builtin_amdgcn_mfma_f32_16x16x32_bf16(a, b0, acc0, 0, 0, 0);
            acc1 = __builtin_amdgcn_mfma_f32_16x16x32_bf16(a, b1, acc1, 0, 0, 0);
        }
        int c0 = l & 15, c1 = 16 + (l & 15);
        int rb = (l >> 4) * 4;
        float m0 = meanS[c0], sd0 = stdS[c0];
        float m1 = meanS[c1], sd1 = stdS[c1];
#pragma unroll
        for (int j = 0; j < 4; ++j) {
            int t = mt * 16 + rb + j;
            Yb[t * 32 + c0] = acc0[j] * (1.0f / 360.0f) * sd0 + m0;
            Yb[t * 32 + c1] = acc1[j] * (1.0f / 360.0f) * sd1 + m1;
        }
    }
    __syncthreads();

    // ---- decode via MFMA: out(720x862) = z(720x32) @ D(32x862), one MFMA per 16x16 tile ----
    {
        const bf16x8* db = (const bf16x8*)Dswz;
        float* outb = out + (size_t)b * T_SEQ * C_INN;
        int ksub = l >> 4;
        for (int mt = w; mt < 45; mt += 16) {
            int t = mt * 16 + (l & 15);
            f32x4 z0 = *(const f32x4*)&Yb[t * 32 + ksub * 8];
            f32x4 z1 = *(const f32x4*)&Yb[t * 32 + ksub * 8 + 4];
            bf16x8 a;
#pragma unroll
            for (int i = 0; i < 4; ++i) { a[i] = f2bf(z0[i]); a[4 + i] = f2bf(z1[i]); }
            int trow = mt * 16 + ksub * 4;
            int cc   = l & 15;
            for (int ct = 0; ct < 54; ++ct) {
                bf16x8 bb = db[ct * 64 + l];
                f32x4 acc = {0.f, 0.f, 0.f, 0.f};
                acc = __builtin_amdgcn_mfma_f32_16x16x32_bf16(a, bb, acc, 0, 0, 0);
                int c = ct * 16 + cc;
                if (c < C_INN) {
#pragma unroll
                    for (int j = 0; j < 4; ++j)
                        outb[(size_t)(trow + j) * C_INN + c] = acc[j];
                }
            }
        }
    }
}

extern "C" void kernel_launch(void* const* d_in, const int* in_sizes, int n_in,
                              void* d_out, int out_size, void* d_ws, size_t ws_size,
                              hipStream_t stream) {
    const float* x   = (const float*)d_in[0];
    const float* P   = (const float*)d_in[1];
    const float* D   = (const float*)d_in[2];
    const float* Wr  = (const float*)d_in[3];
    const float* Wi  = (const float*)d_in[4];
    const float* brr = (const float*)d_in[5];
    const float* bii = (const float*)d_in[6];
    float* out = (float*)d_out;
    float* ws  = (float*)d_ws;

    float* Y     = ws;
    short* Pswz  = (short*)(ws + PSWZ_OFF);
    short* ftabB = (short*)(ws + FTABB_OFF);
    short* itabB = (short*)(ws + ITABB_OFF);
    short* Dswz  = (short*)(ws + DSWZ_OFF);

    k_prep_all<<<1032, 256, 0, stream>>>(P, D, Pswz, ftabB, itabB, Dswz);
    k_encode_mfma<<<(B_SZ * T_SEQ) / 64, 256, 0, stream>>>(x, Pswz, Y);   // 2880 blocks
    k_fused<<<B_SZ, 1024, 0, stream>>>(Y, ftabB, itabB, Dswz, Wr, Wi, brr, bii, out);
}

// Round 5
// 405.960 us; speedup vs baseline: 4.3663x; 1.0579x over previous
//
#include <hip/hip_runtime.h>
#include <math.h>

#define B_SZ   256
#define T_SEQ  720
#define C_INN  862
#define RANK   32
#define FCUT   48
#define GOUT   96
#define KTILES 27            // ceil(862/32) for encode

// ws layout (float offsets):
// [0, 5898240)            (unused; formerly Y)
// [5898240, 5912064)      Pswz : 27648 bf16 shorts (encode B-frags)
// [5912064, 5947392)      ftabB: 70656 bf16 shorts (fwd-DFT A-frags, 96x736)
// [5947392, 6016512)      itabB: 138240 bf16 shorts (iDFT A-frags, 720x192)
// [6016512, 6030336)      Dswz : 27648 bf16 shorts (decode B-frags, 32x864)
#define PSWZ_OFF  (5898240)
#define FTABB_OFF (5912064)
#define ITABB_OFF (5947392)
#define DSWZ_OFF  (6016512)

typedef __attribute__((ext_vector_type(8))) short bf16x8;
typedef __attribute__((ext_vector_type(4))) float f32x4;

__device__ inline short f2bf(float f) {
    union { float f; unsigned u; } v; v.f = f;
    unsigned r = (v.u + 0x7fffu + ((v.u >> 16) & 1u)) >> 16;   // RNE
    return (short)r;
}

// Fills all four precomputed tables. 1032*256 == 138240+70656+27648+27648.
__global__ __launch_bounds__(256) void k_prep_all(const float* __restrict__ P,
                                                  const float* __restrict__ D,
                                                  short* __restrict__ Pswz,
                                                  short* __restrict__ ftabB,
                                                  short* __restrict__ itabB,
                                                  short* __restrict__ Dswz) {
    int idx = blockIdx.x * 256 + threadIdx.x;
    const float TWO_PI = 6.28318530717958647692f;
    if (idx < 138240) {
        // iDFT A-table: A[t][k], t tiles of 16 (45), k=0..191 (6 K-steps)
        int i = idx & 7, l = (idx >> 3) & 63, rest = idx >> 9;
        int ks = rest % 6, mt = rest / 6;
        int t = mt * 16 + (l & 15);
        int k = ks * 32 + ((l >> 4) << 3) + i;
        int g = k >> 1, odd = k & 1;
        float val;
        if (g == 0) {
            val = odd ? 0.0f : 0.5f;
        } else {
            int m = (g * (720 + t)) % 1440;
            float th = TWO_PI * (float)m * (1.0f / 1440.0f);
            val = odd ? sinf(th) : cosf(th);
        }
        itabB[idx] = f2bf(val);
    } else if (idx < 138240 + 70656) {
        // fwd-DFT A-table: A[row][t], row 2f=cos / 2f+1=-sin, t=0..735 (23 K-steps)
        int j = idx - 138240;
        int i = j & 7, l = (j >> 3) & 63, rest = j >> 9;
        int ks = rest % 23, mt = rest / 23;
        int row = mt * 16 + (l & 15);
        int t = ks * 32 + ((l >> 4) << 3) + i;
        int f = row >> 1, odd = row & 1;
        float val = 0.0f;
        if (t < T_SEQ) {
            int m = (f * t) % T_SEQ;
            float th = TWO_PI * (float)m * (1.0f / 720.0f);
            val = odd ? -sinf(th) : cosf(th);
        }
        ftabB[j] = f2bf(val);
    } else if (idx < 138240 + 70656 + 27648) {
        // encode B-frags (verified round 2)
        int j = idx - 138240 - 70656;
        int i = j & 7, lane = (j >> 3) & 63, rest = j >> 9;
        int ct = rest & 1, kt = rest >> 1;
        int k = kt * 32 + ((lane >> 4) << 3) + i;
        int c = ct * 16 + (lane & 15);
        float v = (k < C_INN) ? P[k * RANK + c] : 0.0f;
        Pswz[j] = f2bf(v);
    } else {
        // decode B-frags: tile ct in [0,54), B[k][c] = D[k][ct*16 + (l&15)], k=(l>>4)*8+i
        int j = idx - 138240 - 70656 - 27648;
        int i = j & 7, lane = (j >> 3) & 63, ct = j >> 9;
        int k = ((lane >> 4) << 3) + i;
        int c = ct * 16 + (lane & 15);
        float v = (c < C_INN) ? D[k * C_INN + c] : 0.0f;
        Dswz[j] = f2bf(v);
    }
}

// Mega-kernel: one block per batch. encode(MFMA, x->LDS) -> stats -> normalize ->
// fwdDFT(MFMA) -> mix -> per-tile { iDFT(MFMA) -> denorm -> decode(MFMA) -> store }.
__global__ __launch_bounds__(1024) void k_mega(const float* __restrict__ x,
                                               const short* __restrict__ Pswz,
                                               const short* __restrict__ ftabB,
                                               const short* __restrict__ itabB,
                                               const short* __restrict__ Dswz,
                                               const float* __restrict__ Wr,
                                               const float* __restrict__ Wi,
                                               const float* __restrict__ brr,
                                               const float* __restrict__ bii,
                                               float* __restrict__ out) {
    __shared__ float Yb[736 * 32];       // 94208 B (rows 720..735 zero)
    __shared__ float Fre[FCUT * 32];
    __shared__ float Fim[FCUT * 32];
    __shared__ short OB[6144];           // iDFT B-frags (192x32 bf16)
    __shared__ float red1[32 * 32];
    __shared__ float red2[32 * 32];
    __shared__ float meanS[32], stdS[32], istdS[32];

    int b   = blockIdx.x;
    int tid = threadIdx.x;
    int l   = tid & 63;
    int w   = tid >> 6;                  // wave 0..15
    const float* xb = x + (size_t)b * T_SEQ * C_INN;
    const bf16x8* pb = (const bf16x8*)Pswz;

    // ---- zero tail rows 720..735 ----
    if (tid < 512) Yb[720 * 32 + tid] = 0.0f;

    // ---- encode: Y(720x32) = x_b(720x862) @ P, straight into LDS ----
    {
        int mrow = l & 15;
        int ksub = l >> 4;
        int cd_col   = l & 15;
        int cd_rbase = (l >> 4) * 4;
        for (int mt = w; mt < 45; mt += 16) {
            const float* xr = xb + (size_t)(mt * 16 + mrow) * C_INN;
            f32x4 acc0 = {0.f, 0.f, 0.f, 0.f};
            f32x4 acc1 = {0.f, 0.f, 0.f, 0.f};
            for (int kt = 0; kt < KTILES - 1; ++kt) {
                int kbase = kt * 32 + ksub * 8;
                float2 u0 = *(const float2*)(xr + kbase);
                float2 u1 = *(const float2*)(xr + kbase + 2);
                float2 u2 = *(const float2*)(xr + kbase + 4);
                float2 u3 = *(const float2*)(xr + kbase + 6);
                bf16x8 a;
                a[0] = f2bf(u0.x); a[1] = f2bf(u0.y);
                a[2] = f2bf(u1.x); a[3] = f2bf(u1.y);
                a[4] = f2bf(u2.x); a[5] = f2bf(u2.y);
                a[6] = f2bf(u3.x); a[7] = f2bf(u3.y);
                bf16x8 b0 = pb[(kt * 2 + 0) * 64 + l];
                bf16x8 b1 = pb[(kt * 2 + 1) * 64 + l];
                acc0 = __builtin_amdgcn_mfma_f32_16x16x32_bf16(a, b0, acc0, 0, 0, 0);
                acc1 = __builtin_amdgcn_mfma_f32_16x16x32_bf16(a, b1, acc1, 0, 0, 0);
            }
            {   // tail: kt = 26, valid k = 832..861
                int kbase = 832 + ksub * 8;
                float vals[8];
                float2 u0 = *(const float2*)(xr + kbase);
                float2 u1 = *(const float2*)(xr + kbase + 2);
                float2 u2 = *(const float2*)(xr + kbase + 4);
                vals[0] = u0.x; vals[1] = u0.y;
                vals[2] = u1.x; vals[3] = u1.y;
                vals[4] = u2.x; vals[5] = u2.y;
                if (ksub < 3) {
                    float2 u3 = *(const float2*)(xr + kbase + 6);
                    vals[6] = u3.x; vals[7] = u3.y;
                } else {
                    vals[6] = 0.f; vals[7] = 0.f;
                }
                bf16x8 a;
#pragma unroll
                for (int j = 0; j < 8; ++j) a[j] = f2bf(vals[j]);
                bf16x8 b0 = pb[(26 * 2 + 0) * 64 + l];
                bf16x8 b1 = pb[(26 * 2 + 1) * 64 + l];
                acc0 = __builtin_amdgcn_mfma_f32_16x16x32_bf16(a, b0, acc0, 0, 0, 0);
                acc1 = __builtin_amdgcn_mfma_f32_16x16x32_bf16(a, b1, acc1, 0, 0, 0);
            }
#pragma unroll
            for (int j = 0; j < 4; ++j) {
                Yb[(mt * 16 + cd_rbase + j) * 32 + cd_col]      = acc0[j];
                Yb[(mt * 16 + cd_rbase + j) * 32 + 16 + cd_col] = acc1[j];
            }
        }
    }
    __syncthreads();

    // ---- stats ----
    {
        int r = tid & 31, grp = tid >> 5;
        float s = 0.f, s2 = 0.f;
        for (int t = grp; t < T_SEQ; t += 32) {
            float v = Yb[t * 32 + r];
            s += v; s2 += v * v;
        }
        red1[grp * 32 + r] = s;
        red2[grp * 32 + r] = s2;
    }
    __syncthreads();
    if (tid < 32) {
        float s = 0.f, s2 = 0.f;
        for (int j = 0; j < 32; ++j) { s += red1[j * 32 + tid]; s2 += red2[j * 32 + tid]; }
        float mean = s / 720.0f;
        float var  = (s2 - 720.0f * mean * mean) / 719.0f;
        float sd   = sqrtf(var + 1e-5f);
        meanS[tid] = mean;
        stdS[tid]  = sd;
        istdS[tid] = 1.0f / sd;
    }
    __syncthreads();

    // ---- normalize ----
    for (int e = tid; e < T_SEQ * 32; e += 1024) {
        int r = e & 31;
        Yb[e] = (Yb[e] - meanS[r]) * istdS[r];
    }
    __syncthreads();

    // ---- forward DFT via MFMA: F_all(96x32) = ftab(96x736) @ Yn(736x32); waves 0..11 ----
    if (w < 12) {
        int mt = w >> 1, ct = w & 1;
        int cc = ct * 16 + (l & 15);
        int khalf = (l >> 4) * 8;
        f32x4 acc = {0.f, 0.f, 0.f, 0.f};
        for (int ks = 0; ks < 23; ++ks) {
            bf16x8 a = ((const bf16x8*)ftabB)[(mt * 23 + ks) * 64 + l];
            int kb = ks * 32 + khalf;
            bf16x8 bb;
#pragma unroll
            for (int i = 0; i < 8; ++i) bb[i] = f2bf(Yb[(kb + i) * 32 + cc]);
            acc = __builtin_amdgcn_mfma_f32_16x16x32_bf16(a, bb, acc, 0, 0, 0);
        }
        int rowb = mt * 16 + (l >> 4) * 4;
#pragma unroll
        for (int j = 0; j < 4; ++j) {
            int row = rowb + j;
            int f = row >> 1;
            if (row & 1) Fim[f * 32 + cc] = acc[j];
            else         Fre[f * 32 + cc] = acc[j];
        }
    }
    __syncthreads();

    // ---- mix: O[g][r] = sum_f F[f][r]*W[r][g][f] + b[r][g]; write into OB B-frag layout ----
    {
        int r = tid & 31, gg = tid >> 5;
        for (int g = gg; g < GOUT; g += 32) {
            float are = brr[r * GOUT + g];
            float aim = bii[r * GOUT + g];
            const float4* wr4 = (const float4*)(Wr + ((size_t)r * GOUT + g) * FCUT);
            const float4* wi4 = (const float4*)(Wi + ((size_t)r * GOUT + g) * FCUT);
#pragma unroll 3
            for (int q = 0; q < 12; ++q) {
                float4 wr = wr4[q], wi = wi4[q];
                int f0 = q * 4;
                float fr, fi;
                fr = Fre[(f0 + 0) * 32 + r]; fi = Fim[(f0 + 0) * 32 + r];
                are += fr * wr.x - fi * wi.x;  aim += fr * wi.x + fi * wr.x;
                fr = Fre[(f0 + 1) * 32 + r]; fi = Fim[(f0 + 1) * 32 + r];
                are += fr * wr.y - fi * wi.y;  aim += fr * wi.y + fi * wr.y;
                fr = Fre[(f0 + 2) * 32 + r]; fi = Fim[(f0 + 2) * 32 + r];
                are += fr * wr.z - fi * wi.z;  aim += fr * wi.z + fi * wr.z;
                fr = Fre[(f0 + 3) * 32 + r]; fi = Fim[(f0 + 3) * 32 + r];
                are += fr * wr.w - fi * wi.w;  aim += fr * wi.w + fi * wr.w;
            }
            int ks   = g >> 4;
            int kk   = (2 * g) & 31;          // even
            int lane = (kk >> 3) * 16 + (r & 15);
            int ct   = r >> 4;
            unsigned lo = (unsigned short)f2bf(are);
            unsigned hi = (unsigned short)f2bf(-aim);
            ((unsigned*)OB)[((((ks * 2 + ct) * 64 + lane) * 8) + (kk & 7)) >> 1] = lo | (hi << 16);
        }
    }
    __syncthreads();

    // ---- per-tile: iDFT(MFMA) -> denorm into own Yb tile -> decode(MFMA) -> store ----
    // Each wave owns tile mt (rows mt*16..mt*16+15): writes and re-reads only its own
    // LDS region, so no __syncthreads needed inside the loop (within-wave lgkmcnt order).
    {
        const bf16x8* db = (const bf16x8*)Dswz;
        float* outb = out + (size_t)b * T_SEQ * C_INN;
        int ksub = l >> 4;
        int c0 = l & 15, c1 = 16 + (l & 15);
        int rb = (l >> 4) * 4;
        float m0 = meanS[c0], sd0 = stdS[c0];
        float m1 = meanS[c1], sd1 = stdS[c1];
        for (int mt = w; mt < 45; mt += 16) {
            // iDFT: z tile(16x32) = itab tile(16x192) @ OB(192x32)
            f32x4 acc0 = {0.f, 0.f, 0.f, 0.f};
            f32x4 acc1 = {0.f, 0.f, 0.f, 0.f};
#pragma unroll
            for (int ks = 0; ks < 6; ++ks) {
                bf16x8 a  = ((const bf16x8*)itabB)[(mt * 6 + ks) * 64 + l];
                bf16x8 b0 = *(const bf16x8*)&OB[((ks * 2 + 0) * 64 + l) * 8];
                bf16x8 b1 = *(const bf16x8*)&OB[((ks * 2 + 1) * 64 + l) * 8];
                acc0 = __builtin_amdgcn_mfma_f32_16x16x32_bf16(a, b0, acc0, 0, 0, 0);
                acc1 = __builtin_amdgcn_mfma_f32_16x16x32_bf16(a, b1, acc1, 0, 0, 0);
            }
#pragma unroll
            for (int j = 0; j < 4; ++j) {
                int t = mt * 16 + rb + j;
                Yb[t * 32 + c0] = acc0[j] * (1.0f / 360.0f) * sd0 + m0;
                Yb[t * 32 + c1] = acc1[j] * (1.0f / 360.0f) * sd1 + m1;
            }
            // decode: out tile(16x862) = z tile(16x32) @ D(32x862)
            int t = mt * 16 + (l & 15);
            f32x4 z0 = *(const f32x4*)&Yb[t * 32 + ksub * 8];
            f32x4 z1 = *(const f32x4*)&Yb[t * 32 + ksub * 8 + 4];
            bf16x8 a;
#pragma unroll
            for (int i = 0; i < 4; ++i) { a[i] = f2bf(z0[i]); a[4 + i] = f2bf(z1[i]); }
            int trow = mt * 16 + ksub * 4;
            int cc   = l & 15;
            for (int ct = 0; ct < 54; ++ct) {
                bf16x8 bb = db[ct * 64 + l];
                f32x4 acc = {0.f, 0.f, 0.f, 0.f};
                acc = __builtin_amdgcn_mfma_f32_16x16x32_bf16(a, bb, acc, 0, 0, 0);
                int c = ct * 16 + cc;
                if (c < C_INN) {
#pragma unroll
                    for (int j = 0; j < 4; ++j)
                        outb[(size_t)(trow + j) * C_INN + c] = acc[j];
                }
            }
        }
    }
}

extern "C" void kernel_launch(void* const* d_in, const int* in_sizes, int n_in,
                              void* d_out, int out_size, void* d_ws, size_t ws_size,
                              hipStream_t stream) {
    const float* x   = (const float*)d_in[0];
    const float* P   = (const float*)d_in[1];
    const float* D   = (const float*)d_in[2];
    const float* Wr  = (const float*)d_in[3];
    const float* Wi  = (const float*)d_in[4];
    const float* brr = (const float*)d_in[5];
    const float* bii = (const float*)d_in[6];
    float* out = (float*)d_out;
    float* ws  = (float*)d_ws;

    short* Pswz  = (short*)(ws + PSWZ_OFF);
    short* ftabB = (short*)(ws + FTABB_OFF);
    short* itabB = (short*)(ws + ITABB_OFF);
    short* Dswz  = (short*)(ws + DSWZ_OFF);

    k_prep_all<<<1032, 256, 0, stream>>>(P, D, Pswz, ftabB, itabB, Dswz);
    k_mega<<<B_SZ, 1024, 0, stream>>>(x, Pswz, ftabB, itabB, Dswz, Wr, Wi, brr, bii, out);
}

// Round 6
// 402.201 us; speedup vs baseline: 4.4071x; 1.0093x over previous
//
#include <hip/hip_runtime.h>
#include <math.h>

#define B_SZ   256
#define T_SEQ  720
#define C_INN  862
#define RANK   32
#define FCUT   48
#define GOUT   96
#define KTILES 27            // ceil(862/32) for encode

// ws layout (float offsets):
// [0, 147456)             WmR : 36864 float4 (mix Wr, [(g*12+q)*32+r])
// [147456, 294912)        WmI : 36864 float4 (mix Wi)
// [294912, 5898240)       unused
// [5898240, 5912064)      Pswz : 27648 bf16 shorts (encode B-frags)
// [5912064, 5947392)      ftabB: 70656 bf16 shorts (fwd-DFT A-frags, 96x736)
// [5947392, 6016512)      itabB: 138240 bf16 shorts (iDFT A-frags, 720x192)
// [6016512, 6030336)      Dswz : 27648 bf16 shorts (decode B-frags, 32x864)
#define WMR_OFF   (0)
#define WMI_OFF   (147456)
#define PSWZ_OFF  (5898240)
#define FTABB_OFF (5912064)
#define ITABB_OFF (5947392)
#define DSWZ_OFF  (6016512)

typedef __attribute__((ext_vector_type(8))) short bf16x8;
typedef __attribute__((ext_vector_type(4))) float f32x4;

__device__ inline short f2bf(float f) {
    union { float f; unsigned u; } v; v.f = f;
    unsigned r = (v.u + 0x7fffu + ((v.u >> 16) & 1u)) >> 16;   // RNE
    return (short)r;
}

// Fills the four bf16 tables. 1032*256 == 138240+70656+27648+27648.
__global__ __launch_bounds__(256) void k_prep_all(const float* __restrict__ P,
                                                  const float* __restrict__ D,
                                                  short* __restrict__ Pswz,
                                                  short* __restrict__ ftabB,
                                                  short* __restrict__ itabB,
                                                  short* __restrict__ Dswz) {
    int idx = blockIdx.x * 256 + threadIdx.x;
    const float TWO_PI = 6.28318530717958647692f;
    if (idx < 138240) {
        // iDFT A-table: A[t][k], t tiles of 16 (45), k=0..191 (6 K-steps)
        int i = idx & 7, l = (idx >> 3) & 63, rest = idx >> 9;
        int ks = rest % 6, mt = rest / 6;
        int t = mt * 16 + (l & 15);
        int k = ks * 32 + ((l >> 4) << 3) + i;
        int g = k >> 1, odd = k & 1;
        float val;
        if (g == 0) {
            val = odd ? 0.0f : 0.5f;
        } else {
            int m = (g * (720 + t)) % 1440;
            float th = TWO_PI * (float)m * (1.0f / 1440.0f);
            val = odd ? sinf(th) : cosf(th);
        }
        itabB[idx] = f2bf(val);
    } else if (idx < 138240 + 70656) {
        // fwd-DFT A-table: A[row][t], row 2f=cos / 2f+1=-sin, t=0..735 (23 K-steps)
        int j = idx - 138240;
        int i = j & 7, l = (j >> 3) & 63, rest = j >> 9;
        int ks = rest % 23, mt = rest / 23;
        int row = mt * 16 + (l & 15);
        int t = ks * 32 + ((l >> 4) << 3) + i;
        int f = row >> 1, odd = row & 1;
        float val = 0.0f;
        if (t < T_SEQ) {
            int m = (f * t) % T_SEQ;
            float th = TWO_PI * (float)m * (1.0f / 720.0f);
            val = odd ? -sinf(th) : cosf(th);
        }
        ftabB[j] = f2bf(val);
    } else if (idx < 138240 + 70656 + 27648) {
        // encode B-frags (verified round 2)
        int j = idx - 138240 - 70656;
        int i = j & 7, lane = (j >> 3) & 63, rest = j >> 9;
        int ct = rest & 1, kt = rest >> 1;
        int k = kt * 32 + ((lane >> 4) << 3) + i;
        int c = ct * 16 + (lane & 15);
        float v = (k < C_INN) ? P[k * RANK + c] : 0.0f;
        Pswz[j] = f2bf(v);
    } else {
        // decode B-frags: tile ct in [0,54), B[k][c] = D[k][ct*16 + (l&15)], k=(l>>4)*8+i
        int j = idx - 138240 - 70656 - 27648;
        int i = j & 7, lane = (j >> 3) & 63, ct = j >> 9;
        int k = ((lane >> 4) << 3) + i;
        int c = ct * 16 + (lane & 15);
        float v = (c < C_INN) ? D[k * C_INN + c] : 0.0f;
        Dswz[j] = f2bf(v);
    }
}

// Re-layout Wr/Wi (f32, exact copy) for coalesced mix loads:
// Wm[(g*12+q)*32 + r] = W[r][g][q*4 .. q*4+4)
__global__ __launch_bounds__(256) void k_prep_wmix(const float* __restrict__ Wr,
                                                   const float* __restrict__ Wi,
                                                   float4* __restrict__ WmR,
                                                   float4* __restrict__ WmI) {
    int j = blockIdx.x * 256 + threadIdx.x;
    if (j >= 36864) return;
    int r = j & 31;
    int q = (j >> 5) % 12;
    int g = (j >> 5) / 12;
    size_t src = ((size_t)(r * 96 + g)) * 48 + q * 4;
    WmR[(g * 12 + q) * 32 + r] = *(const float4*)(Wr + src);
    WmI[(g * 12 + q) * 32 + r] = *(const float4*)(Wi + src);
}

// Mega-kernel: one block per batch. encode(MFMA, x->LDS, 3 tiles/wave merged) -> stats ->
// normalize -> fwdDFT(MFMA) -> mix -> per-tile { iDFT(MFMA) -> denorm -> decode(MFMA) -> store }.
__global__ __launch_bounds__(1024) void k_mega(const float* __restrict__ x,
                                               const short* __restrict__ Pswz,
                                               const short* __restrict__ ftabB,
                                               const short* __restrict__ itabB,
                                               const short* __restrict__ Dswz,
                                               const float4* __restrict__ WmR,
                                               const float4* __restrict__ WmI,
                                               const float* __restrict__ brr,
                                               const float* __restrict__ bii,
                                               float* __restrict__ out) {
    __shared__ float Yb[736 * 32];       // 94208 B (rows 720..735 zero)
    __shared__ float Fre[FCUT * 32];
    __shared__ float Fim[FCUT * 32];
    __shared__ short OB[6144];           // iDFT B-frags (192x32 bf16)
    __shared__ float red1[32 * 32];
    __shared__ float red2[32 * 32];
    __shared__ float meanS[32], stdS[32], istdS[32];

    int b   = blockIdx.x;
    int tid = threadIdx.x;
    int l   = tid & 63;
    int w   = tid >> 6;                  // wave 0..15
    const float* xb = x + (size_t)b * T_SEQ * C_INN;
    const bf16x8* pb = (const bf16x8*)Pswz;

    // ---- zero tail rows 720..735 ----
    if (tid < 512) Yb[720 * 32 + tid] = 0.0f;

    // ---- encode: Y(720x32) = x_b(720x862) @ P, 3 row-tiles per wave in one K-loop ----
    {
        int mrow = l & 15;
        int ksub = l >> 4;
        int cd_col   = l & 15;
        int cd_rbase = (l >> 4) * 4;
        int mt0 = w, mt1 = w + 16, mt2 = w + 32;
        bool has3 = (mt2 < 45);
        const float* xr0 = xb + (size_t)(mt0 * 16 + mrow) * C_INN;
        const float* xr1 = xb + (size_t)(mt1 * 16 + mrow) * C_INN;
        const float* xr2 = has3 ? (xb + (size_t)(mt2 * 16 + mrow) * C_INN) : xr0;

        f32x4 acc00 = {0,0,0,0}, acc01 = {0,0,0,0};
        f32x4 acc10 = {0,0,0,0}, acc11 = {0,0,0,0};
        f32x4 acc20 = {0,0,0,0}, acc21 = {0,0,0,0};

#pragma unroll 2
        for (int kt = 0; kt < KTILES - 1; ++kt) {
            int kbase = kt * 32 + ksub * 8;
            float4 u00 = *(const float4*)(xr0 + kbase);
            float4 u01 = *(const float4*)(xr0 + kbase + 4);
            float4 u10 = *(const float4*)(xr1 + kbase);
            float4 u11 = *(const float4*)(xr1 + kbase + 4);
            float4 u20 = *(const float4*)(xr2 + kbase);
            float4 u21 = *(const float4*)(xr2 + kbase + 4);
            bf16x8 b0 = pb[(kt * 2 + 0) * 64 + l];
            bf16x8 b1 = pb[(kt * 2 + 1) * 64 + l];
            bf16x8 a0, a1, a2;
            a0[0]=f2bf(u00.x); a0[1]=f2bf(u00.y); a0[2]=f2bf(u00.z); a0[3]=f2bf(u00.w);
            a0[4]=f2bf(u01.x); a0[5]=f2bf(u01.y); a0[6]=f2bf(u01.z); a0[7]=f2bf(u01.w);
            a1[0]=f2bf(u10.x); a1[1]=f2bf(u10.y); a1[2]=f2bf(u10.z); a1[3]=f2bf(u10.w);
            a1[4]=f2bf(u11.x); a1[5]=f2bf(u11.y); a1[6]=f2bf(u11.z); a1[7]=f2bf(u11.w);
            a2[0]=f2bf(u20.x); a2[1]=f2bf(u20.y); a2[2]=f2bf(u20.z); a2[3]=f2bf(u20.w);
            a2[4]=f2bf(u21.x); a2[5]=f2bf(u21.y); a2[6]=f2bf(u21.z); a2[7]=f2bf(u21.w);
            acc00 = __builtin_amdgcn_mfma_f32_16x16x32_bf16(a0, b0, acc00, 0, 0, 0);
            acc01 = __builtin_amdgcn_mfma_f32_16x16x32_bf16(a0, b1, acc01, 0, 0, 0);
            acc10 = __builtin_amdgcn_mfma_f32_16x16x32_bf16(a1, b0, acc10, 0, 0, 0);
            acc11 = __builtin_amdgcn_mfma_f32_16x16x32_bf16(a1, b1, acc11, 0, 0, 0);
            acc20 = __builtin_amdgcn_mfma_f32_16x16x32_bf16(a2, b0, acc20, 0, 0, 0);
            acc21 = __builtin_amdgcn_mfma_f32_16x16x32_bf16(a2, b1, acc21, 0, 0, 0);
        }
        {   // tail kt=26: valid k = 832..861, guarded float2 loads (no OOB past tensor end)
            int kbase = 832 + ksub * 8;
            bf16x8 b0 = pb[(26 * 2 + 0) * 64 + l];
            bf16x8 b1 = pb[(26 * 2 + 1) * 64 + l];
            const float* xrs[3] = {xr0, xr1, xr2};
            f32x4* accs[3][2] = {{&acc00,&acc01},{&acc10,&acc11},{&acc20,&acc21}};
#pragma unroll
            for (int tt = 0; tt < 3; ++tt) {
                const float* xr = xrs[tt];
                float vals[8];
                float2 u0 = *(const float2*)(xr + kbase);
                float2 u1 = *(const float2*)(xr + kbase + 2);
                float2 u2 = *(const float2*)(xr + kbase + 4);
                vals[0] = u0.x; vals[1] = u0.y;
                vals[2] = u1.x; vals[3] = u1.y;
                vals[4] = u2.x; vals[5] = u2.y;
                if (ksub < 3) {
                    float2 u3 = *(const float2*)(xr + kbase + 6);
                    vals[6] = u3.x; vals[7] = u3.y;
                } else {
                    vals[6] = 0.f; vals[7] = 0.f;
                }
                bf16x8 a;
#pragma unroll
                for (int j = 0; j < 8; ++j) a[j] = f2bf(vals[j]);
                *accs[tt][0] = __builtin_amdgcn_mfma_f32_16x16x32_bf16(a, b0, *accs[tt][0], 0, 0, 0);
                *accs[tt][1] = __builtin_amdgcn_mfma_f32_16x16x32_bf16(a, b1, *accs[tt][1], 0, 0, 0);
            }
        }
#pragma unroll
        for (int j = 0; j < 4; ++j) {
            Yb[(mt0 * 16 + cd_rbase + j) * 32 + cd_col]      = acc00[j];
            Yb[(mt0 * 16 + cd_rbase + j) * 32 + 16 + cd_col] = acc01[j];
            Yb[(mt1 * 16 + cd_rbase + j) * 32 + cd_col]      = acc10[j];
            Yb[(mt1 * 16 + cd_rbase + j) * 32 + 16 + cd_col] = acc11[j];
        }
        if (has3) {
#pragma unroll
            for (int j = 0; j < 4; ++j) {
                Yb[(mt2 * 16 + cd_rbase + j) * 32 + cd_col]      = acc20[j];
                Yb[(mt2 * 16 + cd_rbase + j) * 32 + 16 + cd_col] = acc21[j];
            }
        }
    }
    __syncthreads();

    // ---- stats ----
    {
        int r = tid & 31, grp = tid >> 5;
        float s = 0.f, s2 = 0.f;
        for (int t = grp; t < T_SEQ; t += 32) {
            float v = Yb[t * 32 + r];
            s += v; s2 += v * v;
        }
        red1[grp * 32 + r] = s;
        red2[grp * 32 + r] = s2;
    }
    __syncthreads();
    if (tid < 32) {
        float s = 0.f, s2 = 0.f;
        for (int j = 0; j < 32; ++j) { s += red1[j * 32 + tid]; s2 += red2[j * 32 + tid]; }
        float mean = s / 720.0f;
        float var  = (s2 - 720.0f * mean * mean) / 719.0f;
        float sd   = sqrtf(var + 1e-5f);
        meanS[tid] = mean;
        stdS[tid]  = sd;
        istdS[tid] = 1.0f / sd;
    }
    __syncthreads();

    // ---- normalize ----
    for (int e = tid; e < T_SEQ * 32; e += 1024) {
        int r = e & 31;
        Yb[e] = (Yb[e] - meanS[r]) * istdS[r];
    }
    __syncthreads();

    // ---- forward DFT via MFMA: F_all(96x32) = ftab(96x736) @ Yn(736x32); waves 0..11 ----
    if (w < 12) {
        int mt = w >> 1, ct = w & 1;
        int cc = ct * 16 + (l & 15);
        int khalf = (l >> 4) * 8;
        f32x4 acc = {0.f, 0.f, 0.f, 0.f};
        for (int ks = 0; ks < 23; ++ks) {
            bf16x8 a = ((const bf16x8*)ftabB)[(mt * 23 + ks) * 64 + l];
            int kb = ks * 32 + khalf;
            bf16x8 bb;
#pragma unroll
            for (int i = 0; i < 8; ++i) bb[i] = f2bf(Yb[(kb + i) * 32 + cc]);
            acc = __builtin_amdgcn_mfma_f32_16x16x32_bf16(a, bb, acc, 0, 0, 0);
        }
        int rowb = mt * 16 + (l >> 4) * 4;
#pragma unroll
        for (int j = 0; j < 4; ++j) {
            int row = rowb + j;
            int f = row >> 1;
            if (row & 1) Fim[f * 32 + cc] = acc[j];
            else         Fre[f * 32 + cc] = acc[j];
        }
    }
    __syncthreads();

    // ---- mix: O[g][r] = sum_f F[f][r]*W[r][g][f] + b[r][g]; coalesced Wmix loads ----
    {
        int r = tid & 31, gg = tid >> 5;
        for (int g = gg; g < GOUT; g += 32) {
            float are = brr[r * GOUT + g];
            float aim = bii[r * GOUT + g];
            const float4* wr4 = WmR + (size_t)g * 384 + r;   // [(g*12+q)*32 + r]
            const float4* wi4 = WmI + (size_t)g * 384 + r;
#pragma unroll 3
            for (int q = 0; q < 12; ++q) {
                float4 wr = wr4[q * 32], wi = wi4[q * 32];
                int f0 = q * 4;
                float fr, fi;
                fr = Fre[(f0 + 0) * 32 + r]; fi = Fim[(f0 + 0) * 32 + r];
                are += fr * wr.x - fi * wi.x;  aim += fr * wi.x + fi * wr.x;
                fr = Fre[(f0 + 1) * 32 + r]; fi = Fim[(f0 + 1) * 32 + r];
                are += fr * wr.y - fi * wi.y;  aim += fr * wi.y + fi * wr.y;
                fr = Fre[(f0 + 2) * 32 + r]; fi = Fim[(f0 + 2) * 32 + r];
                are += fr * wr.z - fi * wi.z;  aim += fr * wi.z + fi * wr.z;
                fr = Fre[(f0 + 3) * 32 + r]; fi = Fim[(f0 + 3) * 32 + r];
                are += fr * wr.w - fi * wi.w;  aim += fr * wi.w + fi * wr.w;
            }
            int ks   = g >> 4;
            int kk   = (2 * g) & 31;          // even
            int lane = (kk >> 3) * 16 + (r & 15);
            int ct   = r >> 4;
            unsigned lo = (unsigned short)f2bf(are);
            unsigned hi = (unsigned short)f2bf(-aim);
            ((unsigned*)OB)[((((ks * 2 + ct) * 64 + lane) * 8) + (kk & 7)) >> 1] = lo | (hi << 16);
        }
    }
    __syncthreads();

    // ---- per-tile: iDFT(MFMA) -> denorm into own Yb tile -> decode(MFMA) -> store ----
    {
        const bf16x8* db = (const bf16x8*)Dswz;
        float* outb = out + (size_t)b * T_SEQ * C_INN;
        int ksub = l >> 4;
        int c0 = l & 15, c1 = 16 + (l & 15);
        int rb = (l >> 4) * 4;
        float m0 = meanS[c0], sd0 = stdS[c0];
        float m1 = meanS[c1], sd1 = stdS[c1];
        for (int mt = w; mt < 45; mt += 16) {
            // iDFT: z tile(16x32) = itab tile(16x192) @ OB(192x32)
            f32x4 acc0 = {0.f, 0.f, 0.f, 0.f};
            f32x4 acc1 = {0.f, 0.f, 0.f, 0.f};
#pragma unroll
            for (int ks = 0; ks < 6; ++ks) {
                bf16x8 a  = ((const bf16x8*)itabB)[(mt * 6 + ks) * 64 + l];
                bf16x8 b0 = *(const bf16x8*)&OB[((ks * 2 + 0) * 64 + l) * 8];
                bf16x8 b1 = *(const bf16x8*)&OB[((ks * 2 + 1) * 64 + l) * 8];
                acc0 = __builtin_amdgcn_mfma_f32_16x16x32_bf16(a, b0, acc0, 0, 0, 0);
                acc1 = __builtin_amdgcn_mfma_f32_16x16x32_bf16(a, b1, acc1, 0, 0, 0);
            }
#pragma unroll
            for (int j = 0; j < 4; ++j) {
                int t = mt * 16 + rb + j;
                Yb[t * 32 + c0] = acc0[j] * (1.0f / 360.0f) * sd0 + m0;
                Yb[t * 32 + c1] = acc1[j] * (1.0f / 360.0f) * sd1 + m1;
            }
            // decode: out tile(16x862) = z tile(16x32) @ D(32x862)
            int t = mt * 16 + (l & 15);
            f32x4 z0 = *(const f32x4*)&Yb[t * 32 + ksub * 8];
            f32x4 z1 = *(const f32x4*)&Yb[t * 32 + ksub * 8 + 4];
            bf16x8 a;
#pragma unroll
            for (int i = 0; i < 4; ++i) { a[i] = f2bf(z0[i]); a[4 + i] = f2bf(z1[i]); }
            int trow = mt * 16 + ksub * 4;
            int cc   = l & 15;
            for (int ct = 0; ct < 54; ++ct) {
                bf16x8 bb = db[ct * 64 + l];
                f32x4 acc = {0.f, 0.f, 0.f, 0.f};
                acc = __builtin_amdgcn_mfma_f32_16x16x32_bf16(a, bb, acc, 0, 0, 0);
                int c = ct * 16 + cc;
                if (c < C_INN) {
#pragma unroll
                    for (int j = 0; j < 4; ++j)
                        outb[(size_t)(trow + j) * C_INN + c] = acc[j];
                }
            }
        }
    }
}

extern "C" void kernel_launch(void* const* d_in, const int* in_sizes, int n_in,
                              void* d_out, int out_size, void* d_ws, size_t ws_size,
                              hipStream_t stream) {
    const float* x   = (const float*)d_in[0];
    const float* P   = (const float*)d_in[1];
    const float* D   = (const float*)d_in[2];
    const float* Wr  = (const float*)d_in[3];
    const float* Wi  = (const float*)d_in[4];
    const float* brr = (const float*)d_in[5];
    const float* bii = (const float*)d_in[6];
    float* out = (float*)d_out;
    float* ws  = (float*)d_ws;

    float4* WmR  = (float4*)(ws + WMR_OFF);
    float4* WmI  = (float4*)(ws + WMI_OFF);
    short* Pswz  = (short*)(ws + PSWZ_OFF);
    short* ftabB = (short*)(ws + FTABB_OFF);
    short* itabB = (short*)(ws + ITABB_OFF);
    short* Dswz  = (short*)(ws + DSWZ_OFF);

    k_prep_all<<<1032, 256, 0, stream>>>(P, D, Pswz, ftabB, itabB, Dswz);
    k_prep_wmix<<<144, 256, 0, stream>>>(Wr, Wi, WmR, WmI);
    k_mega<<<B_SZ, 1024, 0, stream>>>(x, Pswz, ftabB, itabB, Dswz, WmR, WmI, brr, bii, out);
}